// Round 9
// baseline (2619.476 us; speedup 1.0000x reference)
//
#include <hip/hip_runtime.h>
#include <hip/hip_fp16.h>
#include <cstddef>

#define TT 2048   // time steps
#define BB 256    // batch
#define DD 32     // input dim
#define HH 64     // hidden
#define GG 256    // 4*H

__device__ __forceinline__ float sigmf(float v)  { return 1.0f / (1.0f + __expf(-v)); }
__device__ __forceinline__ float tanhf_(float v) { return 2.0f / (1.0f + __expf(-2.0f * v)) - 1.0f; }
__device__ __forceinline__ __half2 f_as_h2(float f) { union { float f; __half2 h; } u; u.f = f; return u.h; }
__device__ __forceinline__ float lo_f(__half2 h) { return __low2float(h); }
__device__ __forceinline__ float hi_f(__half2 h) { return __high2float(h); }

// One block per batch row; 128 threads = 2 waves. Lane = unit (64 units).
// Wave 0: layer-1 recurrence (one step ahead) + output projection (redundant
//         per-lane dot, no reduce). Wave 1: layer-2 recurrence.
// Each lane owns ALL 4 GATES of its unit over the FULL K: zero shuffles
// anywhere; cross-wave h via 512B LDS double buffer; barrier syncs 2 waves.
// This deliberately trades issue slots (idle SIMDs) for the removal of the
// R2-R8 stall structure (8-wave barrier + 6-deep shuffle chains per step).
__global__ __launch_bounds__(128, 1)
void dlstm_kernel(const float* __restrict__ x,
                  const float* __restrict__ W1, const float* __restrict__ U1,
                  const float* __restrict__ b1,
                  const float* __restrict__ W2, const float* __restrict__ U2,
                  const float* __restrict__ b2,
                  const float* __restrict__ Wd, const float* __restrict__ bd,
                  float* __restrict__ out)
{
    const int tid = threadIdx.x, b = blockIdx.x;
    const int wid = tid >> 6, u = tid & 63;

    __shared__ __align__(16) __half h1b[2][HH];
    __shared__ __align__(16) __half h2b[2][HH];

    if (wid == 0) { h1b[0][u] = __float2half(0.f); h1b[1][u] = __float2half(0.f); }
    else          { h2b[0][u] = __float2half(0.f); h2b[1][u] = __float2half(0.f); }
    __syncthreads();

    if (wid == 0) {
        // ================= layer-1 + projection wave =================
        __half2 w1[4][DD/2], u1[4][HH/2], wd[HH/2];
        float bz[4];
        #pragma unroll
        for (int g = 0; g < 4; ++g) {
            #pragma unroll
            for (int j = 0; j < DD/2; ++j)
                w1[g][j] = __floats2half2_rn(W1[(2*j)*GG + g*HH + u],
                                             W1[(2*j+1)*GG + g*HH + u]);
            #pragma unroll
            for (int j = 0; j < HH/2; ++j)
                u1[g][j] = __floats2half2_rn(U1[(2*j)*GG + g*HH + u],
                                             U1[(2*j+1)*GG + g*HH + u]);
            bz[g] = b1[g*HH + u];
        }
        #pragma unroll
        for (int j = 0; j < HH/2; ++j) wd[j] = __floats2half2_rn(Wd[2*j], Wd[2*j+1]);
        const float bd0 = bd[0];
        float c1 = 0.f;

        const float* xr = x + (size_t)b * TT * DD;   // all lanes same addr: bcast
        float4 xf[8];
        #pragma unroll
        for (int q = 0; q < 8; ++q) xf[q] = ((const float4*)xr)[q];

        for (int n = 0; n < TT + 2; ++n) {
            const int p = n & 1;
            if (n < TT) {
                // prefetch x(n+1) first: in flight under the whole step
                const float4* nx = (const float4*)(xr + (size_t)((n+1 < TT) ? n+1 : n) * DD);
                float4 xn[8];
                #pragma unroll
                for (int q = 0; q < 8; ++q) xn[q] = nx[q];

                __half2 xh[16];
                #pragma unroll
                for (int q = 0; q < 8; ++q) {
                    xh[2*q]   = __floats2half2_rn(xf[q].x, xf[q].y);
                    xh[2*q+1] = __floats2half2_rn(xf[q].z, xf[q].w);
                }
                // h1(n-1) broadcast read (8x ds_read_b128, same addr all lanes)
                const float4* hp4 = (const float4*)h1b[p];
                __half2 hh[32];
                #pragma unroll
                for (int j = 0; j < 8; ++j) {
                    float4 r = hp4[j];
                    hh[4*j+0] = f_as_h2(r.x); hh[4*j+1] = f_as_h2(r.y);
                    hh[4*j+2] = f_as_h2(r.z); hh[4*j+3] = f_as_h2(r.w);
                }
                // 4 gate dots, full K in-lane; 3 fp16 chains (<=16 deep), f32 combine
                float zg[4];
                #pragma unroll
                for (int g = 0; g < 4; ++g) {
                    __half2 sx = __float2half2_rn(0.f), sa = sx, sb = sx;
                    #pragma unroll
                    for (int j = 0; j < 16; ++j) sx = __hfma2(w1[g][j], xh[j], sx);
                    #pragma unroll
                    for (int j = 0; j < 16; ++j) sa = __hfma2(u1[g][j], hh[j], sa);
                    #pragma unroll
                    for (int j = 16; j < 32; ++j) sb = __hfma2(u1[g][j], hh[j], sb);
                    __half2 sh = __hadd2(sa, sb);
                    zg[g] = (lo_f(sx) + hi_f(sx)) + (lo_f(sh) + hi_f(sh)) + bz[g];
                }
                float gi = sigmf(zg[0]), gf = sigmf(zg[1]);
                float gc = tanhf_(zg[2]), go = sigmf(zg[3]);
                c1 = gf * c1 + gi * gc;
                float h = go * tanhf_(c1);
                h1b[p ^ 1][u] = __float2half(h);   // own unit, in-lane

                #pragma unroll
                for (int q = 0; q < 8; ++q) xf[q] = xn[q];
            }
            if (n >= 2) {
                // out(n-2) = sigmoid(h2(n-2)·Wd + bd); h2(n-2) lives in h2b[p].
                // All lanes compute the dot redundantly: no reduce shuffles.
                const float4* h2p4 = (const float4*)h2b[p];
                __half2 pa = __float2half2_rn(0.f), pb = pa;
                #pragma unroll
                for (int j = 0; j < 4; ++j) {
                    float4 r = h2p4[j];
                    pa = __hfma2(wd[4*j+0], f_as_h2(r.x), pa);
                    pa = __hfma2(wd[4*j+1], f_as_h2(r.y), pa);
                    pa = __hfma2(wd[4*j+2], f_as_h2(r.z), pa);
                    pa = __hfma2(wd[4*j+3], f_as_h2(r.w), pa);
                }
                #pragma unroll
                for (int j = 4; j < 8; ++j) {
                    float4 r = h2p4[j];
                    pb = __hfma2(wd[4*j+0], f_as_h2(r.x), pb);
                    pb = __hfma2(wd[4*j+1], f_as_h2(r.y), pb);
                    pb = __hfma2(wd[4*j+2], f_as_h2(r.z), pb);
                    pb = __hfma2(wd[4*j+3], f_as_h2(r.w), pb);
                }
                float v = (lo_f(pa) + hi_f(pa)) + (lo_f(pb) + hi_f(pb));
                if (u == 0) out[(size_t)b * TT + (n - 2)] = sigmf(v + bd0);
            }
            __syncthreads();
        }
    } else {
        // ================= layer-2 wave =================
        __half2 w2[4][HH/2], u2[4][HH/2];
        float bz[4];
        #pragma unroll
        for (int g = 0; g < 4; ++g) {
            #pragma unroll
            for (int j = 0; j < HH/2; ++j) {
                w2[g][j] = __floats2half2_rn(W2[(2*j)*GG + g*HH + u],
                                             W2[(2*j+1)*GG + g*HH + u]);
                u2[g][j] = __floats2half2_rn(U2[(2*j)*GG + g*HH + u],
                                             U2[(2*j+1)*GG + g*HH + u]);
            }
            bz[g] = b2[g*HH + u];
        }
        float c2 = 0.f;

        for (int n = 0; n < TT + 2; ++n) {
            const int p = n & 1;
            if (n >= 1 && n <= TT) {
                const float4* h1p4 = (const float4*)h1b[p];   // h1(n-1)
                const float4* h2p4 = (const float4*)h2b[p];   // h2(n-2)
                __half2 hh1[32], hh2[32];
                #pragma unroll
                for (int j = 0; j < 8; ++j) {
                    float4 r1 = h1p4[j], r2 = h2p4[j];
                    hh1[4*j+0] = f_as_h2(r1.x); hh1[4*j+1] = f_as_h2(r1.y);
                    hh1[4*j+2] = f_as_h2(r1.z); hh1[4*j+3] = f_as_h2(r1.w);
                    hh2[4*j+0] = f_as_h2(r2.x); hh2[4*j+1] = f_as_h2(r2.y);
                    hh2[4*j+2] = f_as_h2(r2.z); hh2[4*j+3] = f_as_h2(r2.w);
                }
                float zg[4];
                #pragma unroll
                for (int g = 0; g < 4; ++g) {
                    __half2 wa = __float2half2_rn(0.f), wb = wa, ua = wa, ub = wa;
                    #pragma unroll
                    for (int j = 0; j < 16; ++j) wa = __hfma2(w2[g][j], hh1[j], wa);
                    #pragma unroll
                    for (int j = 16; j < 32; ++j) wb = __hfma2(w2[g][j], hh1[j], wb);
                    #pragma unroll
                    for (int j = 0; j < 16; ++j) ua = __hfma2(u2[g][j], hh2[j], ua);
                    #pragma unroll
                    for (int j = 16; j < 32; ++j) ub = __hfma2(u2[g][j], hh2[j], ub);
                    __half2 sw = __hadd2(wa, wb), su = __hadd2(ua, ub);
                    zg[g] = (lo_f(sw) + hi_f(sw)) + (lo_f(su) + hi_f(su)) + bz[g];
                }
                float gi = sigmf(zg[0]), gf = sigmf(zg[1]);
                float gc = tanhf_(zg[2]), go = sigmf(zg[3]);
                c2 = gf * c2 + gi * gc;
                float h = go * tanhf_(c2);
                h2b[p ^ 1][u] = __float2half(h);   // h2(n-1)
            }
            __syncthreads();
        }
    }
}

extern "C" void kernel_launch(void* const* d_in, const int* in_sizes, int n_in,
                              void* d_out, int out_size, void* d_ws, size_t ws_size,
                              hipStream_t stream) {
    const float* x  = (const float*)d_in[0];
    const float* W1 = (const float*)d_in[1];
    const float* U1 = (const float*)d_in[2];
    const float* b1 = (const float*)d_in[3];
    const float* W2 = (const float*)d_in[4];
    const float* U2 = (const float*)d_in[5];
    const float* b2 = (const float*)d_in[6];
    const float* Wd = (const float*)d_in[7];
    const float* bd = (const float*)d_in[8];
    float* out = (float*)d_out;

    dlstm_kernel<<<dim3(BB), dim3(128), 0, stream>>>(
        x, W1, U1, b1, W2, U2, b2, Wd, bd, out);
}